// Round 3
// baseline (1108.419 us; speedup 1.0000x reference)
//
#include <hip/hip_runtime.h>

// Cost-volume concatenation:
// out[c2][d][h][x] (shape 64 x 128 x 128 x 256, f32):
//   shift = 112 - d;  idx = x + shift;  valid = 0 <= idx < 256
//   c2 <  32: valid ? left[c2][h][x]        : 0
//   c2 >= 32: valid ? right[c2-32][h][idx]  : 0
// Pure data movement, write-bound (~1.07 GB stores, 8 MB input).

#define CC_W 256
#define CC_H 128
#define CC_C 32
#define CC_D 128

__global__ __launch_bounds__(256) void cost_concat_kernel(
    const float* __restrict__ left,
    const float* __restrict__ right,
    float* __restrict__ out,
    int total4) {
  const int stride = gridDim.x * blockDim.x;
  for (int i = blockIdx.x * blockDim.x + threadIdx.x; i < total4; i += stride) {
    // flat float index = i*4; decompose (all power-of-2 strides)
    const int x4 = i & 63;            // 64 float4 per W=256 row
    const int h  = (i >> 6) & 127;
    const int d  = (i >> 13) & 127;
    const int c2 = i >> 20;           // 0..63
    const int x  = x4 << 2;
    const int i0 = x + 112 - d;       // idx of element .x

    float4 v;
    if (c2 < CC_C) {
      // left half: aligned float4 load, mask by validity of idx
      const float* src = left + (((c2 * CC_H) + h) << 8);
      v = *reinterpret_cast<const float4*>(src + x);
      v.x = ((unsigned)(i0 + 0) < 256u) ? v.x : 0.0f;
      v.y = ((unsigned)(i0 + 1) < 256u) ? v.y : 0.0f;
      v.z = ((unsigned)(i0 + 2) < 256u) ? v.z : 0.0f;
      v.w = ((unsigned)(i0 + 3) < 256u) ? v.w : 0.0f;
    } else {
      // right half: shifted gather; clamp index (stays in-bounds), mask result
      const float* src = right + ((((c2 - CC_C) * CC_H) + h) << 8);
      int j0 = min(max(i0 + 0, 0), 255);
      int j1 = min(max(i0 + 1, 0), 255);
      int j2 = min(max(i0 + 2, 0), 255);
      int j3 = min(max(i0 + 3, 0), 255);
      v.x = ((unsigned)(i0 + 0) < 256u) ? src[j0] : 0.0f;
      v.y = ((unsigned)(i0 + 1) < 256u) ? src[j1] : 0.0f;
      v.z = ((unsigned)(i0 + 2) < 256u) ? src[j2] : 0.0f;
      v.w = ((unsigned)(i0 + 3) < 256u) ? src[j3] : 0.0f;
    }
    reinterpret_cast<float4*>(out)[i] = v;
  }
}

extern "C" void kernel_launch(void* const* d_in, const int* in_sizes, int n_in,
                              void* d_out, int out_size, void* d_ws, size_t ws_size,
                              hipStream_t stream) {
  const float* left  = (const float*)d_in[0];
  const float* right = (const float*)d_in[1];
  float* out = (float*)d_out;

  const int total4 = (2 * CC_C) * CC_D * CC_H * (CC_W / 4);  // 67,108,864
  const int block = 256;
  const int grid = 2048;  // 8 blocks/CU on 256 CUs, grid-stride the rest
  hipLaunchKernelGGL(cost_concat_kernel, dim3(grid), dim3(block), 0, stream,
                     left, right, out, total4);
}